// Round 4
// baseline (436.730 us; speedup 1.0000x reference)
//
#include <hip/hip_runtime.h>

typedef unsigned short u16;
typedef unsigned int   u32;
typedef __attribute__((ext_vector_type(8))) short bf16x8;   // 8 bf16 = 4 VGPRs
typedef __attribute__((ext_vector_type(4))) float f32x4;

#define S_LEN 2048
#define B_SZ  2
#define H_DIM 2048
#define NH_   16
#define HN_   128
#define M_TOK 4096          /* tokens, row = s*B + b */
#define NQKV  6144
#define NT_   (S_LEN / 64)  /* 32 Q-tiles of 64 rows */

// raw barrier: does NOT drain vmcnt -- staged loads stay in flight across it
#define BAR      asm volatile("s_barrier" ::: "memory")
#define WAITV(n) asm volatile("s_waitcnt vmcnt(" #n ")" ::: "memory")
// pre-barrier drain hint for 12-read phases (m201 template)
#define HINT_L8  asm volatile("s_waitcnt lgkmcnt(8)" ::: "memory")

// float -> bf16 round-to-nearest-even
__device__ __forceinline__ u16 f2bf(float f) {
    u32 x = __float_as_uint(f);
    return (u16)((x + 0x7fffu + ((x >> 16) & 1u)) >> 16);
}

// async global->LDS, 16 B per lane
__device__ __forceinline__ void async16(const void* g, void* l) {
    __builtin_amdgcn_global_load_lds((const __attribute__((address_space(1))) void*)g,
                                     (__attribute__((address_space(3))) void*)l,
                                     16, 0, 0);
}

// one launch converting all three fp32 tensors to bf16 (each size % 4 == 0)
__global__ __launch_bounds__(256) void cvt3(
    const float* __restrict__ a, u16* __restrict__ oa, int na,   // float4-groups
    const float* __restrict__ b, u16* __restrict__ ob, int nb,
    const float* __restrict__ c, u16* __restrict__ oc, int nc)
{
    int g = blockIdx.x * 256 + threadIdx.x;
    const float* in; u16* out; int idx;
    if (g < na)           { in = a; out = oa; idx = g; }
    else if (g < na + nb) { in = b; out = ob; idx = g - na; }
    else if (g < na + nb + nc) { in = c; out = oc; idx = g - na - nb; }
    else return;
    int i = idx * 4;
    float4 v = *(const float4*)&in[i];
    ushort4 o;
    o.x = f2bf(v.x); o.y = f2bf(v.y); o.z = f2bf(v.z); o.w = f2bf(v.w);
    *(ushort4*)&out[i] = o;
}

// ---------------------------------------------------------------------------
// 256x256 8-phase bf16 GEMM, C = A[M,K] @ W[N,K]^T, K = 2048.
// R4: stage tile indices made AFFINE in the loop variable (masks removed,
// final iteration peeled with literal wrapped tiles) so LLVM strength-reduces
// the 16 staging addresses into running pointers -- kills ~700 cyc/K-tile of
// 64-bit multiply chains (VALUBusy 14%). lgkmcnt(8) hint on 12-read phases.
// Barrier/vmcnt ledger identical to R3 (verified): snake quadrants, 24
// ds_read_b128/K-tile/wave, depth-3 staging, WAITV(6) at ph4/ph8 only.
// LDS XOR-swizzle slot^=row&7 as inverse-swizzled global source (T2).
// EPI=0: fp32 store. EPI=1: qkv scatter (bias, Q-scale, V transpose).
// ---------------------------------------------------------------------------
template<int EPI, int MM, int NN>
__global__ __launch_bounds__(512, 2) void gemm8(
    const u16* __restrict__ A, const u16* __restrict__ W,
    const float* __restrict__ bias, float* __restrict__ Cout,
    u16* __restrict__ Qb, u16* __restrict__ Kb, u16* __restrict__ Vt)
{
    constexpr int K   = 2048;
    constexpr int NKT = K / 64;            // 32 K-tiles
    constexpr int NBN = NN / 256;
    constexpr int NWG = (MM / 256) * NBN;  // % 8 == 0 for all our shapes

    __shared__ __align__(16) u16 sA[2][256 * 64];   // 2 x 32 KB
    __shared__ __align__(16) u16 sB[2][256 * 64];   // 2 x 32 KB

    const int t = threadIdx.x, l = t & 63, w = t >> 6;
    const int quad = l >> 4, ln = l & 15;
    const int qw_r = w >> 2, qw_c = w & 3;   // wave grid 2x4 inside a quadrant

    int wg = blockIdx.x;
    wg = (wg & 7) * (NWG / 8) + (wg >> 3);   // bijective XCD swizzle (NWG%8==0)
    const int m0 = (wg / NBN) * 256, n0 = (wg % NBN) * 256;

    // ---- staging: thread t owns 16B chunks c=t and c=t+512 of each half-tile.
    // chunk c: row-in-half r=c>>3, PHYSICAL slot ps=c&7 holds LOGICAL kchunk
    // ps^(r&7)  (inverse swizzle on the global source; LDS dest stays linear).
    const int srow = t >> 3;                          // 0..63 (chunk c=t)
    const int skc  = (t & 7) ^ (srow & 7);            // swizzled k-chunk
    const u16* pA = A + (size_t)(m0 + srow) * K + skc * 8;
    const u16* pB = W + (size_t)(n0 + srow) * K + skc * 8;
    // chunk c=t+512: row srow+64, same slot swizzle (64 ≡ 0 mod 8) -> +64*K.

#define STAGE_A(db, h, kt)                                                        \
    do {                                                                          \
        async16(pA + (size_t)(h) * 128 * K + (size_t)(kt) * 64,                   \
                &sA[db][(h) * 8192 + t * 8]);                                     \
        async16(pA + (size_t)(h) * 128 * K + (size_t)64 * K + (size_t)(kt) * 64,  \
                &sA[db][(h) * 8192 + t * 8 + 4096]);                              \
    } while (0)
#define STAGE_B(db, h, kt)                                                        \
    do {                                                                          \
        async16(pB + (size_t)(h) * 128 * K + (size_t)(kt) * 64,                   \
                &sB[db][(h) * 8192 + t * 8]);                                     \
        async16(pB + (size_t)(h) * 128 * K + (size_t)64 * K + (size_t)(kt) * 64,  \
                &sB[db][(h) * 8192 + t * 8 + 4096]);                              \
    } while (0)

    // ---- ds_read fragment addressing (u16 indices), swizzled slot on read
    const int aBase = (qw_r * 64 + ln) * 64;
    const int bBase = (qw_c * 32 + ln) * 64;
    int swz[2];
#pragma unroll
    for (int ks = 0; ks < 2; ++ks)
        swz[ks] = ((ks * 4 + quad) ^ (ln & 7)) << 3;

    bf16x8 af[4][2];    // A frags: 4 m-frags x 2 k-steps (live for 2 phases)
    bf16x8 bS0[2][2];   // B set 0: n-half 0 frags (live ph1..ph4)
    bf16x8 bS1[2][2];   // B set 1: n-half 1 frags (live ph2..ph3)

#define RD_A(db, mq)                                                              \
    do {                                                                          \
        _Pragma("unroll") for (int mf = 0; mf < 4; ++mf)                          \
        _Pragma("unroll") for (int ks = 0; ks < 2; ++ks)                          \
            af[mf][ks] = *(const bf16x8*)&sA[db][aBase + (mq) * 8192 + mf * 1024  \
                                                + swz[ks]];                       \
    } while (0)
#define RD_B(db, nq, SET)                                                         \
    do {                                                                          \
        _Pragma("unroll") for (int nf = 0; nf < 2; ++nf)                          \
        _Pragma("unroll") for (int ks = 0; ks < 2; ++ks)                          \
            SET[nf][ks] = *(const bf16x8*)&sB[db][bBase + (nq) * 8192 + nf * 1024 \
                                                 + swz[ks]];                      \
    } while (0)

    f32x4 acc[4][4][2];   // [quadrant mq*2+nq][m-frag][n-frag]
#pragma unroll
    for (int q = 0; q < 4; ++q)
#pragma unroll
        for (int mf = 0; mf < 4; ++mf)
#pragma unroll
            for (int nf = 0; nf < 2; ++nf)
#pragma unroll
                for (int r = 0; r < 4; ++r) acc[q][mf][nf][r] = 0.f;

#define MM16(q, SET)                                                              \
    do {                                                                          \
        __builtin_amdgcn_s_setprio(1);                                            \
        _Pragma("unroll") for (int mf = 0; mf < 4; ++mf)                          \
        _Pragma("unroll") for (int nf = 0; nf < 2; ++nf)                          \
        _Pragma("unroll") for (int ks = 0; ks < 2; ++ks)                          \
            acc[q][mf][nf] = __builtin_amdgcn_mfma_f32_16x16x32_bf16(             \
                af[mf][ks], SET[nf][ks], acc[q][mf][nf], 0, 0, 0);                \
        __builtin_amdgcn_s_setprio(0);                                            \
    } while (0)

// one 2-K-tile iteration; T1/T2/T3 are the stage tile indices (affine in the
// main loop so LSR forms running pointers; peeled tail passes literals)
#define KBODY(T1, T2, T3)                                                         \
    do {                                                                          \
        /* ph1: quadrant (0,0) of even tile (buf0); reads A-h0 + B-h0 */          \
        RD_A(0, 0); RD_B(0, 0, bS0);                                              \
        STAGE_A(1, 1, T1);                  /* A1(t+1): buf1-Ah1 rel prev-ph7 */  \
        HINT_L8;                                                                  \
        BAR; MM16(0, bS0); BAR;                                                   \
        /* ph2: (0,1); reads B-h1 (A kept) */                                     \
        RD_B(0, 1, bS1);                                                          \
        STAGE_A(0, 0, T2);                  /* A0(t+2): buf0-Ah0 rel ph1 */       \
        BAR; MM16(1, bS1); BAR;                                                   \
        /* ph3: (1,1); reads A-h1 (B set1 kept) */                                \
        RD_A(0, 1);                                                               \
        STAGE_B(0, 0, T2);                  /* B0(t+2): buf0-Bh0 rel ph1 */       \
        BAR; MM16(3, bS1); BAR;                                                   \
        /* ph4: (1,0); no reads -- no opening barrier */                          \
        STAGE_B(0, 1, T2);                  /* B1(t+2): buf0-Bh1 rel ph2 */       \
        MM16(2, bS0);                                                             \
        WAITV(6);                           /* forces T+1's 4 halves; 3 fly */    \
        BAR;                                                                      \
        /* ph5: (0,0) of odd tile (buf1) */                                       \
        RD_A(1, 0); RD_B(1, 0, bS0);                                              \
        STAGE_A(0, 1, T2);                  /* A1(t+2): buf0-Ah1 rel ph3 */       \
        HINT_L8;                                                                  \
        BAR; MM16(0, bS0); BAR;                                                   \
        /* ph6: (0,1) */                                                          \
        RD_B(1, 1, bS1);                                                          \
        STAGE_A(1, 0, T3);                  /* A0(t+3): buf1-Ah0 rel ph5 */       \
        BAR; MM16(1, bS1); BAR;                                                   \
        /* ph7: (1,1) */                                                          \
        RD_A(1, 1);                                                               \
        STAGE_B(1, 0, T3);                  /* B0(t+3): buf1-Bh0 rel ph5 */       \
        BAR; MM16(3, bS1); BAR;                                                   \
        /* ph8: (1,0) -- no reads, no opening barrier */                          \
        STAGE_B(1, 1, T3);                  /* B1(t+3): buf1-Bh1 rel ph6 */       \
        MM16(2, bS0);                                                             \
        WAITV(6);                           /* forces T+2's 4 halves */           \
        BAR;                                                                      \
    } while (0)

    // ---- prologue: T0 fully (A0,B0,B1,A1) + T1's A0,B0,B1; force T0, 3 fly
    STAGE_A(0, 0, 0); STAGE_B(0, 0, 0); STAGE_B(0, 1, 0); STAGE_A(0, 1, 0);
    STAGE_A(1, 0, 1); STAGE_B(1, 0, 1); STAGE_B(1, 1, 1);
    WAITV(6);
    BAR;

#pragma unroll 1
    for (int i = 0; i < NKT / 2 - 1; ++i) {   // K-tiles 0..29; no wrap -> affine
        const int tt = 2 * i;
        KBODY(tt + 1, tt + 2, tt + 3);
    }
    // peeled final iteration (K-tiles 30,31): wrapped stage targets as
    // literals (tile 0/1 dummy refill -- same semantics as R3's masked form)
    KBODY(31, 0, 1);
#undef KBODY
#undef STAGE_A
#undef STAGE_B
#undef RD_A
#undef RD_B
#undef MM16

    // C/D layout: col = lane&15, row = (lane>>4)*4 + reg   [verified m89/m91]
    if constexpr (EPI == 0) {
#pragma unroll
        for (int q = 0; q < 4; ++q) {
            const int mq = q >> 1, nq = q & 1;
#pragma unroll
            for (int mf = 0; mf < 4; ++mf)
#pragma unroll
                for (int nf = 0; nf < 2; ++nf) {
                    int col = n0 + nq * 128 + qw_c * 32 + nf * 16 + ln;
#pragma unroll
                    for (int r = 0; r < 4; ++r) {
                        int row = m0 + mq * 128 + qw_r * 64 + mf * 16 + quad * 4 + r;
                        Cout[(size_t)row * NN + col] = acc[q][mf][nf][r];
                    }
                }
        }
    } else {
        // fold 1/sqrt(128) * log2(e) into Q so softmax uses exp2
        const float kQS = 0.08838834764831845f * 1.44269504088896340f;
#pragma unroll
        for (int q = 0; q < 4; ++q) {
            const int mq = q >> 1, nq = q & 1;
#pragma unroll
            for (int nf = 0; nf < 2; ++nf) {
                int col  = n0 + nq * 128 + qw_c * 32 + nf * 16 + ln;
                int head = col / 384;
                int g    = col - head * 384;
                int sec  = g >> 7;        // 0=q 1=k 2=v (uniform over 16-span)
                int d    = g & 127;
                float bv = bias[col];
#pragma unroll
                for (int mf = 0; mf < 4; ++mf)
#pragma unroll
                    for (int r = 0; r < 4; ++r) {
                        int tok = m0 + mq * 128 + qw_r * 64 + mf * 16 + quad * 4 + r;
                        int s = tok >> 1, bb = tok & 1;
                        float v = acc[q][mf][nf][r] + bv;
                        if (sec == 0)
                            Qb[((size_t)(bb * NH_ + head) * S_LEN + s) * HN_ + d] = f2bf(v * kQS);
                        else if (sec == 1)
                            Kb[((size_t)(bb * NH_ + head) * S_LEN + s) * HN_ + d] = f2bf(v);
                        else  // V stored transposed [d][s] for PV B-fragments
                            Vt[((size_t)(bb * NH_ + head) * HN_ + d) * S_LEN + s] = f2bf(v);
                    }
            }
        }
    }
}

// ---------------------------------------------------------------------------
// MFMA flash attention, load-balanced + double-buffered (unchanged).
// Block j processes Q-tiles qt = NT-1-j and qt = j: every block does exactly
// NT+1 kt-iterations -> zero tail at 2 blocks/CU.
// ---------------------------------------------------------------------------
__global__ __launch_bounds__(256) void attn_mfma(
    const u16* __restrict__ Qb, const u16* __restrict__ Kb,
    const u16* __restrict__ Vt, u16* __restrict__ Ctx)
{
    __shared__ __align__(16) u16 Ks[2][16 * 64 * 8];   // 2 x 16 KB
    __shared__ __align__(16) u16 Vs[2][16 * 64 * 8];   // 2 x 16 KB
    __shared__ __align__(16) u16 Psm[4][16][72];       // 9.25 KB, per-wave

    const int t = threadIdx.x, l = t & 63, w = t >> 6;
    const int quad = l >> 4, ln = l & 15;
    const int j = blockIdx.x;       // 0..15
    const int n = blockIdx.y, b = blockIdx.z;
    const u16* Qh = Qb + (size_t)(b * NH_ + n) * S_LEN * HN_;
    const u16* Kh = Kb + (size_t)(b * NH_ + n) * S_LEN * HN_;
    const u16* Vh = Vt + (size_t)(b * NH_ + n) * HN_ * S_LEN;

#pragma unroll 1
    for (int phase = 0; phase < 2; ++phase) {
        const int qt = phase ? j : (NT_ - 1 - j);
        const int q0 = qt * 64;

        // stage Q (64x128) into Ks[1]; stage K/V kt=0 into set 0
#pragma unroll
        for (int i = 0; i < 4; ++i)
            async16(&Qh[(size_t)(q0 + i * 16 + ln) * HN_ + w * 32 + quad * 8],
                    &Ks[1][((i * 4 + w) * 64 + l) * 8]);
#pragma unroll
        for (int i = 0; i < 4; ++i) {
            async16(&Kh[(size_t)(i * 16 + ln) * HN_ + w * 32 + quad * 8],
                    &Ks[0][((i * 4 + w) * 64 + l) * 8]);
            int dv = i * 4 + w, dt = dv >> 1, ks = dv & 1;
            async16(&Vh[(size_t)(dt * 16 + ln) * S_LEN + ks * 32 + quad * 8],
                    &Vs[0][(dv * 64 + l) * 8]);
        }
        __syncthreads();

        bf16x8 qf[4];
#pragma unroll
        for (int ks = 0; ks < 4; ++ks)
            qf[ks] = *(const bf16x8*)&Ks[1][((w * 4 + ks) * 64 + l) * 8];
        __syncthreads();   // all qf reads done before kt=1 prefetch lands in Ks[1]

        float m_i[4], l_i[4];
        f32x4 acco[8];
#pragma unroll
        for (int r = 0; r < 4; ++r) { m_i[r] = -1e30f; l_i[r] = 0.f; }
#pragma unroll
        for (int dt = 0; dt < 8; ++dt)
#pragma unroll
            for (int r = 0; r < 4; ++r) acco[dt][r] = 0.f;

#pragma unroll 1
        for (int kt = 0; kt <= qt; ++kt) {
            const int cur = kt & 1;

            // prefetch kt+1 into the other set (overlaps with compute below)
            if (kt < qt) {
                const int nxt = cur ^ 1;
#pragma unroll
                for (int i = 0; i < 4; ++i) {
                    async16(&Kh[(size_t)((kt + 1) * 64 + i * 16 + ln) * HN_ + w * 32 + quad * 8],
                            &Ks[nxt][((i * 4 + w) * 64 + l) * 8]);
                    int dv = i * 4 + w, dt = dv >> 1, ks = dv & 1;
                    async16(&Vh[(size_t)(dt * 16 + ln) * S_LEN + (kt + 1) * 64 + ks * 32 + quad * 8],
                            &Vs[nxt][(dv * 64 + l) * 8]);
                }
            }

            // S = Q K^T : 16 q rows x 64 k tokens per wave
            f32x4 sc[4];
#pragma unroll
            for (int nt = 0; nt < 4; ++nt)
#pragma unroll
                for (int r = 0; r < 4; ++r) sc[nt][r] = 0.f;
#pragma unroll
            for (int nt = 0; nt < 4; ++nt)
#pragma unroll
                for (int ks = 0; ks < 4; ++ks) {
                    bf16x8 kf = *(const bf16x8*)&Ks[cur][((nt * 4 + ks) * 64 + l) * 8];
                    sc[nt] = __builtin_amdgcn_mfma_f32_16x16x32_bf16(qf[ks], kf, sc[nt], 0, 0, 0);
                }

            if (kt == qt) {   // only the diagonal tile is partially masked
#pragma unroll
                for (int nt = 0; nt < 4; ++nt)
#pragma unroll
                    for (int r = 0; r < 4; ++r)
                        if (nt * 16 + ln > w * 16 + quad * 4 + r) sc[nt][r] = -1e30f;
            }

            // online softmax (base-2; scale folded into Q)
            float corr[4];
#pragma unroll
            for (int r = 0; r < 4; ++r) {
                float mx = fmaxf(fmaxf(sc[0][r], sc[1][r]), fmaxf(sc[2][r], sc[3][r]));
                mx = fmaxf(mx, __shfl_xor(mx, 1));
                mx = fmaxf(mx, __shfl_xor(mx, 2));
                mx = fmaxf(mx, __shfl_xor(mx, 4));
                mx = fmaxf(mx, __shfl_xor(mx, 8));
                float mnew = fmaxf(m_i[r], mx);
                corr[r] = exp2f(m_i[r] - mnew);
                m_i[r] = mnew;
            }
#pragma unroll
            for (int r = 0; r < 4; ++r) {
                float ps = 0.f;
#pragma unroll
                for (int nt = 0; nt < 4; ++nt) {
                    float p = exp2f(sc[nt][r] - m_i[r]);
                    ps += p;
                    Psm[w][quad * 4 + r][nt * 16 + ln] = f2bf(p);
                }
                l_i[r] = l_i[r] * corr[r] + ps;   // lane-partial l
            }

            // rescale O, then O += P @ V
#pragma unroll
            for (int dt = 0; dt < 8; ++dt)
#pragma unroll
                for (int r = 0; r < 4; ++r) acco[dt][r] *= corr[r];

            bf16x8 pf[2];
#pragma unroll
            for (int ks = 0; ks < 2; ++ks)
                pf[ks] = *(const bf16x8*)&Psm[w][ln][ks * 32 + quad * 8];
#pragma unroll
            for (int dt = 0; dt < 8; ++dt)
#pragma unroll
                for (int ks = 0; ks < 2; ++ks) {
                    bf16x8 vf = *(const bf16x8*)&Vs[cur][((dt * 2 + ks) * 64 + l) * 8];
                    acco[dt] = __builtin_amdgcn_mfma_f32_16x16x32_bf16(pf[ks], vf, acco[dt], 0, 0, 0);
                }
            __syncthreads();   // release cur set; drain the kt+1 prefetch
        }

        // finalize: reduce lane-partial l over the 16-lane quad group
#pragma unroll
        for (int r = 0; r < 4; ++r) {
            float s = l_i[r];
            s += __shfl_xor(s, 1);
            s += __shfl_xor(s, 2);
            s += __shfl_xor(s, 4);
            s += __shfl_xor(s, 8);
            l_i[r] = 1.f / s;
        }
#pragma unroll
        for (int dt = 0; dt < 8; ++dt)
#pragma unroll
            for (int r = 0; r < 4; ++r) {
                int srow = q0 + w * 16 + quad * 4 + r;
                Ctx[((size_t)(srow * B_SZ + b)) * H_DIM + n * HN_ + dt * 16 + ln] =
                    f2bf(acco[dt][r] * l_i[r]);
            }
    }
}

__global__ void copy_bias(const float* __restrict__ b_dense, float* __restrict__ out)
{
    int t = blockIdx.x * 256 + threadIdx.x;
    if (t < H_DIM) out[(size_t)M_TOK * H_DIM + t] = b_dense[t];
}

extern "C" void kernel_launch(void* const* d_in, const int* in_sizes, int n_in,
                              void* d_out, int out_size, void* d_ws, size_t ws_size,
                              hipStream_t stream)
{
    const float* hs      = (const float*)d_in[0];
    /* d_in[1] attention_mask: compile-time causal, ignored */
    const float* w_qkv   = (const float*)d_in[2];
    const float* b_qkv   = (const float*)d_in[3];
    const float* w_dense = (const float*)d_in[4];
    const float* b_dense = (const float*)d_in[5];
    float* out = (float*)d_out;

    u16* hs_bf = (u16*)d_ws;                           //  16.8 MB
    u16* wq_bf = hs_bf + (size_t)M_TOK * H_DIM;        //  25.2 MB
    u16* wd_bf = wq_bf + (size_t)NQKV * H_DIM;         //   8.4 MB
    u16* Qb    = wd_bf + (size_t)H_DIM * H_DIM;        //  16.8 MB  [b][n][s][d]
    u16* Kb    = Qb    + (size_t)M_TOK * H_DIM;        //  16.8 MB  [b][n][s][d]
    u16* Vt    = Kb    + (size_t)M_TOK * H_DIM;        //  16.8 MB  [b][n][d][s]
    u16* Ctx   = Vt    + (size_t)M_TOK * H_DIM;        //  16.8 MB  [s][b][h]

    const int g1 = (M_TOK * H_DIM) / 4;   // float4-groups per tensor
    const int g2 = (NQKV * H_DIM) / 4;
    const int g3 = (H_DIM * H_DIM) / 4;
    cvt3<<<(g1 + g2 + g3 + 255) / 256, 256, 0, stream>>>(
        hs, hs_bf, g1, w_qkv, wq_bf, g2, w_dense, wd_bf, g3);

    gemm8<1, M_TOK, NQKV><<<(M_TOK / 256) * (NQKV / 256), 512, 0, stream>>>(
        hs_bf, wq_bf, b_qkv, nullptr, Qb, Kb, Vt);

    attn_mfma<<<dim3(NT_ / 2, NH_, B_SZ), 256, 0, stream>>>(Qb, Kb, Vt, Ctx);

    gemm8<0, M_TOK, H_DIM><<<(M_TOK / 256) * (H_DIM / 256), 512, 0, stream>>>(
        Ctx, wd_bf, nullptr, out, nullptr, nullptr, nullptr);

    copy_bias<<<(H_DIM + 255) / 256, 256, 0, stream>>>(b_dense, out);
}

// Round 5
// 427.933 us; speedup vs baseline: 1.0206x; 1.0206x over previous
//
#include <hip/hip_runtime.h>

typedef unsigned short u16;
typedef unsigned int   u32;
typedef __attribute__((ext_vector_type(8))) short bf16x8;   // 8 bf16 = 4 VGPRs
typedef __attribute__((ext_vector_type(4))) float f32x4;

#define S_LEN 2048
#define B_SZ  2
#define H_DIM 2048
#define NH_   16
#define HN_   128
#define M_TOK 4096          /* tokens, row = s*B + b */
#define NQKV  6144
#define NT_   (S_LEN / 64)  /* 32 Q-tiles of 64 rows */

// raw barrier: does NOT drain vmcnt -- staged loads stay in flight across it
#define BAR      asm volatile("s_barrier" ::: "memory")
#define WAITV(n) asm volatile("s_waitcnt vmcnt(" #n ")" ::: "memory")

// float -> bf16 round-to-nearest-even
__device__ __forceinline__ u16 f2bf(float f) {
    u32 x = __float_as_uint(f);
    return (u16)((x + 0x7fffu + ((x >> 16) & 1u)) >> 16);
}

// async global->LDS, 16 B per lane
__device__ __forceinline__ void async16(const void* g, void* l) {
    __builtin_amdgcn_global_load_lds((const __attribute__((address_space(1))) void*)g,
                                     (__attribute__((address_space(3))) void*)l,
                                     16, 0, 0);
}

// one launch converting all three fp32 tensors to bf16 (each size % 4 == 0)
__global__ __launch_bounds__(256) void cvt3(
    const float* __restrict__ a, u16* __restrict__ oa, int na,   // float4-groups
    const float* __restrict__ b, u16* __restrict__ ob, int nb,
    const float* __restrict__ c, u16* __restrict__ oc, int nc)
{
    int g = blockIdx.x * 256 + threadIdx.x;
    const float* in; u16* out; int idx;
    if (g < na)           { in = a; out = oa; idx = g; }
    else if (g < na + nb) { in = b; out = ob; idx = g - na; }
    else if (g < na + nb + nc) { in = c; out = oc; idx = g - na - nb; }
    else return;
    int i = idx * 4;
    float4 v = *(const float4*)&in[i];
    ushort4 o;
    o.x = f2bf(v.x); o.y = f2bf(v.y); o.z = f2bf(v.z); o.w = f2bf(v.w);
    *(ushort4*)&out[i] = o;
}

// ---------------------------------------------------------------------------
// 256x256 8-phase bf16 GEMM, C = A[M,K] @ W[N,K]^T, K = 2048.
// R5: HOISTED-READ schedule -- each phase = {STAGE Xi; MFMA(q); issue NEXT
// phase's ds_reads; BAR}. Reads fly during the MFMA drain + barrier wait, so
// LDS windows overlap matrix windows instead of serializing (R3 measured the
// SUM, 5550 cyc/K-tile; target the MAX, ~3300). Stage map X1..X8 identical to
// R3. WAITV(4) at ph3/ph7 (before BAR): queue sim leftover4+8issued=12,
// drain-8 = exactly the next K-tile's 4 halves. Ledger (hand-verified):
//   RAW: S1'(ph4) after ph3 WAITV+BAR; S1''(ph8) after ph7 WAITV+BAR;
//        S2/S3 read buf regions forced >=1 iter earlier.
//   WAR: every STAGE Xi issues >=1 closing-BAR after its region's reads
//        retire (reads retire before their consuming MFMA's issue).
//   Registers: af overwritten h0->h1 only after last h0-MFMA (program order);
//        same for bS0/bS1 -- single sets, no VGPR growth.
// One barrier per phase (8/iter). Snake quadrants (0,0)(0,1)(1,1)(1,0);
// 24 ds_read_b128/K-tile/wave. LDS XOR-swizzle slot^=row&7 via
// inverse-swizzled global source (T2). setprio around MFMA (T5).
// EPI=0: fp32 store. EPI=1: qkv scatter (bias, Q-scale, V transpose).
// ---------------------------------------------------------------------------
template<int EPI, int MM, int NN>
__global__ __launch_bounds__(512, 2) void gemm8(
    const u16* __restrict__ A, const u16* __restrict__ W,
    const float* __restrict__ bias, float* __restrict__ Cout,
    u16* __restrict__ Qb, u16* __restrict__ Kb, u16* __restrict__ Vt)
{
    constexpr int K   = 2048;
    constexpr int NKT = K / 64;            // 32 K-tiles
    constexpr int NBN = NN / 256;
    constexpr int NWG = (MM / 256) * NBN;  // % 8 == 0 for all our shapes

    __shared__ __align__(16) u16 sA[2][256 * 64];   // 2 x 32 KB
    __shared__ __align__(16) u16 sB[2][256 * 64];   // 2 x 32 KB

    const int t = threadIdx.x, l = t & 63, w = t >> 6;
    const int quad = l >> 4, ln = l & 15;
    const int qw_r = w >> 2, qw_c = w & 3;   // wave grid 2x4 inside a quadrant

    int wg = blockIdx.x;
    wg = (wg & 7) * (NWG / 8) + (wg >> 3);   // bijective XCD swizzle (NWG%8==0)
    const int m0 = (wg / NBN) * 256, n0 = (wg % NBN) * 256;

    // ---- staging: thread t owns 16B chunks c=t and c=t+512 of each half-tile.
    // chunk c: row-in-half r=c>>3, PHYSICAL slot ps=c&7 holds LOGICAL kchunk
    // ps^(r&7)  (inverse swizzle on the global source; LDS dest stays linear).
    const int srow = t >> 3;                          // 0..63 (chunk c=t)
    const int skc  = (t & 7) ^ (srow & 7);            // swizzled k-chunk
    const u16* pA = A + (size_t)(m0 + srow) * K + skc * 8;
    const u16* pB = W + (size_t)(n0 + srow) * K + skc * 8;
    // chunk c=t+512: row srow+64, same slot swizzle (64 ≡ 0 mod 8) -> +64*K.

#define STAGE_A(db, h, kt)                                                        \
    do {                                                                          \
        async16(pA + (size_t)(h) * 128 * K + (size_t)(kt) * 64,                   \
                &sA[db][(h) * 8192 + t * 8]);                                     \
        async16(pA + (size_t)(h) * 128 * K + (size_t)64 * K + (size_t)(kt) * 64,  \
                &sA[db][(h) * 8192 + t * 8 + 4096]);                              \
    } while (0)
#define STAGE_B(db, h, kt)                                                        \
    do {                                                                          \
        async16(pB + (size_t)(h) * 128 * K + (size_t)(kt) * 64,                   \
                &sB[db][(h) * 8192 + t * 8]);                                     \
        async16(pB + (size_t)(h) * 128 * K + (size_t)64 * K + (size_t)(kt) * 64,  \
                &sB[db][(h) * 8192 + t * 8 + 4096]);                              \
    } while (0)

    // ---- ds_read fragment addressing (u16 indices), swizzled slot on read
    const int aBase = (qw_r * 64 + ln) * 64;
    const int bBase = (qw_c * 32 + ln) * 64;
    int swz[2];
#pragma unroll
    for (int ks = 0; ks < 2; ++ks)
        swz[ks] = ((ks * 4 + quad) ^ (ln & 7)) << 3;

    bf16x8 af[4][2];    // A frags (holds h0 or h1; overwritten after last use)
    bf16x8 bS0[2][2];   // B n-half-0 frags
    bf16x8 bS1[2][2];   // B n-half-1 frags

#define RD_A(db, mq)                                                              \
    do {                                                                          \
        _Pragma("unroll") for (int mf = 0; mf < 4; ++mf)                          \
        _Pragma("unroll") for (int ks = 0; ks < 2; ++ks)                          \
            af[mf][ks] = *(const bf16x8*)&sA[db][aBase + (mq) * 8192 + mf * 1024  \
                                                + swz[ks]];                       \
    } while (0)
#define RD_B(db, nq, SET)                                                         \
    do {                                                                          \
        _Pragma("unroll") for (int nf = 0; nf < 2; ++nf)                          \
        _Pragma("unroll") for (int ks = 0; ks < 2; ++ks)                          \
            SET[nf][ks] = *(const bf16x8*)&sB[db][bBase + (nq) * 8192 + nf * 1024 \
                                                 + swz[ks]];                      \
    } while (0)

    f32x4 acc[4][4][2];   // [quadrant mq*2+nq][m-frag][n-frag]
#pragma unroll
    for (int q = 0; q < 4; ++q)
#pragma unroll
        for (int mf = 0; mf < 4; ++mf)
#pragma unroll
            for (int nf = 0; nf < 2; ++nf)
#pragma unroll
                for (int r = 0; r < 4; ++r) acc[q][mf][nf][r] = 0.f;

#define MM16(q, SET)                                                              \
    do {                                                                          \
        __builtin_amdgcn_s_setprio(1);                                            \
        _Pragma("unroll") for (int mf = 0; mf < 4; ++mf)                          \
        _Pragma("unroll") for (int nf = 0; nf < 2; ++nf)                          \
        _Pragma("unroll") for (int ks = 0; ks < 2; ++ks)                          \
            acc[q][mf][nf] = __builtin_amdgcn_mfma_f32_16x16x32_bf16(             \
                af[mf][ks], SET[nf][ks], acc[q][mf][nf], 0, 0, 0);                \
        __builtin_amdgcn_s_setprio(0);                                            \
    } while (0)

    // ---- prologue: T0 fully + T1's A0,B0,B1; force T0 (leave 6); first S1
    STAGE_A(0, 0, 0); STAGE_B(0, 0, 0); STAGE_B(0, 1, 0); STAGE_A(0, 1, 0);
    STAGE_A(1, 0, 1); STAGE_B(1, 0, 1); STAGE_B(1, 1, 1);
    WAITV(6);
    BAR;
    RD_A(0, 0); RD_B(0, 0, bS0);            // S1 for first ph1 (exposed once)

#pragma unroll 1
    for (int i = 0; i < NKT / 2; ++i) {
        const int tt  = 2 * i;
        const int tp1 = tt + 1;                 // never wraps (tt <= 30)
        const int tp2 = (tt + 2) & (NKT - 1);   // wraps to dummy refill at end
        const int tp3 = (tt + 3) & (NKT - 1);

        // ph1: q(0,0) tile t buf0  [af=h0, bS0 from prev ph8 / prologue]
        STAGE_A(1, 1, tp1);                 // X1: buf1-Ah1 (readers done prev ph7)
        MM16(0, bS0);
        RD_B(0, 1, bS1);                    // S2 -> ph2
        BAR;
        // ph2: q(0,1)
        STAGE_A(0, 0, tp2);                 // X2: buf0-Ah0 (read by prev S1'' <= ph1)
        MM16(1, bS1);
        RD_A(0, 1);                         // S3: af -> h1, for ph3+ph4
        BAR;
        // ph3: q(1,1)
        STAGE_B(0, 0, tp2);                 // X3: buf0-Bh0 (read by prev S1'' <= ph1)
        MM16(3, bS1);
        WAITV(4);                           // forces tile t+1's 4 halves
        BAR;
        // ph4: q(1,0)  [af=h1, bS0 still tile t]
        STAGE_B(0, 1, tp2);                 // X4: buf0-Bh1 (read by S2 <= ph2)
        MM16(2, bS0);
        RD_A(1, 0); RD_B(1, 0, bS0);        // S1': buf1 tile t+1 (forced @ph3)
        BAR;
        // ph5: q(0,0) tile t+1 buf1
        STAGE_A(0, 1, tp2);                 // X5: buf0-Ah1 (read by S3 <= ph3)
        MM16(0, bS0);
        RD_B(1, 1, bS1);                    // S2'
        BAR;
        // ph6: q(0,1)
        STAGE_A(1, 0, tp3);                 // X6: buf1-Ah0 (read by S1' <= ph5)
        MM16(1, bS1);
        RD_A(1, 1);                         // S3'
        BAR;
        // ph7: q(1,1)
        STAGE_B(1, 0, tp3);                 // X7: buf1-Bh0 (read by S1' <= ph5)
        MM16(3, bS1);
        WAITV(4);                           // forces tile t+2's 4 halves
        BAR;
        // ph8: q(1,0)
        STAGE_B(1, 1, tp3);                 // X8: buf1-Bh1 (read by S2' <= ph6)
        MM16(2, bS0);
        RD_A(0, 0); RD_B(0, 0, bS0);        // S1'': buf0 tile t+2 (forced @ph7)
        BAR;
    }
#undef STAGE_A
#undef STAGE_B
#undef RD_A
#undef RD_B
#undef MM16

    // C/D layout: col = lane&15, row = (lane>>4)*4 + reg   [verified m89/m91]
    if constexpr (EPI == 0) {
#pragma unroll
        for (int q = 0; q < 4; ++q) {
            const int mq = q >> 1, nq = q & 1;
#pragma unroll
            for (int mf = 0; mf < 4; ++mf)
#pragma unroll
                for (int nf = 0; nf < 2; ++nf) {
                    int col = n0 + nq * 128 + qw_c * 32 + nf * 16 + ln;
#pragma unroll
                    for (int r = 0; r < 4; ++r) {
                        int row = m0 + mq * 128 + qw_r * 64 + mf * 16 + quad * 4 + r;
                        Cout[(size_t)row * NN + col] = acc[q][mf][nf][r];
                    }
                }
        }
    } else {
        // fold 1/sqrt(128) * log2(e) into Q so softmax uses exp2
        const float kQS = 0.08838834764831845f * 1.44269504088896340f;
#pragma unroll
        for (int q = 0; q < 4; ++q) {
            const int mq = q >> 1, nq = q & 1;
#pragma unroll
            for (int nf = 0; nf < 2; ++nf) {
                int col  = n0 + nq * 128 + qw_c * 32 + nf * 16 + ln;
                int head = col / 384;
                int g    = col - head * 384;
                int sec  = g >> 7;        // 0=q 1=k 2=v (uniform over 16-span)
                int d    = g & 127;
                float bv = bias[col];
#pragma unroll
                for (int mf = 0; mf < 4; ++mf)
#pragma unroll
                    for (int r = 0; r < 4; ++r) {
                        int tok = m0 + mq * 128 + qw_r * 64 + mf * 16 + quad * 4 + r;
                        int s = tok >> 1, bb = tok & 1;
                        float v = acc[q][mf][nf][r] + bv;
                        if (sec == 0)
                            Qb[((size_t)(bb * NH_ + head) * S_LEN + s) * HN_ + d] = f2bf(v * kQS);
                        else if (sec == 1)
                            Kb[((size_t)(bb * NH_ + head) * S_LEN + s) * HN_ + d] = f2bf(v);
                        else  // V stored transposed [d][s] for PV B-fragments
                            Vt[((size_t)(bb * NH_ + head) * HN_ + d) * S_LEN + s] = f2bf(v);
                    }
            }
        }
    }
}

// ---------------------------------------------------------------------------
// MFMA flash attention, load-balanced + double-buffered (unchanged).
// Block j processes Q-tiles qt = NT-1-j and qt = j: every block does exactly
// NT+1 kt-iterations -> zero tail at 2 blocks/CU.
// ---------------------------------------------------------------------------
__global__ __launch_bounds__(256) void attn_mfma(
    const u16* __restrict__ Qb, const u16* __restrict__ Kb,
    const u16* __restrict__ Vt, u16* __restrict__ Ctx)
{
    __shared__ __align__(16) u16 Ks[2][16 * 64 * 8];   // 2 x 16 KB
    __shared__ __align__(16) u16 Vs[2][16 * 64 * 8];   // 2 x 16 KB
    __shared__ __align__(16) u16 Psm[4][16][72];       // 9.25 KB, per-wave

    const int t = threadIdx.x, l = t & 63, w = t >> 6;
    const int quad = l >> 4, ln = l & 15;
    const int j = blockIdx.x;       // 0..15
    const int n = blockIdx.y, b = blockIdx.z;
    const u16* Qh = Qb + (size_t)(b * NH_ + n) * S_LEN * HN_;
    const u16* Kh = Kb + (size_t)(b * NH_ + n) * S_LEN * HN_;
    const u16* Vh = Vt + (size_t)(b * NH_ + n) * HN_ * S_LEN;

#pragma unroll 1
    for (int phase = 0; phase < 2; ++phase) {
        const int qt = phase ? j : (NT_ - 1 - j);
        const int q0 = qt * 64;

        // stage Q (64x128) into Ks[1]; stage K/V kt=0 into set 0
#pragma unroll
        for (int i = 0; i < 4; ++i)
            async16(&Qh[(size_t)(q0 + i * 16 + ln) * HN_ + w * 32 + quad * 8],
                    &Ks[1][((i * 4 + w) * 64 + l) * 8]);
#pragma unroll
        for (int i = 0; i < 4; ++i) {
            async16(&Kh[(size_t)(i * 16 + ln) * HN_ + w * 32 + quad * 8],
                    &Ks[0][((i * 4 + w) * 64 + l) * 8]);
            int dv = i * 4 + w, dt = dv >> 1, ks = dv & 1;
            async16(&Vh[(size_t)(dt * 16 + ln) * S_LEN + ks * 32 + quad * 8],
                    &Vs[0][(dv * 64 + l) * 8]);
        }
        __syncthreads();

        bf16x8 qf[4];
#pragma unroll
        for (int ks = 0; ks < 4; ++ks)
            qf[ks] = *(const bf16x8*)&Ks[1][((w * 4 + ks) * 64 + l) * 8];
        __syncthreads();   // all qf reads done before kt=1 prefetch lands in Ks[1]

        float m_i[4], l_i[4];
        f32x4 acco[8];
#pragma unroll
        for (int r = 0; r < 4; ++r) { m_i[r] = -1e30f; l_i[r] = 0.f; }
#pragma unroll
        for (int dt = 0; dt < 8; ++dt)
#pragma unroll
            for (int r = 0; r < 4; ++r) acco[dt][r] = 0.f;

#pragma unroll 1
        for (int kt = 0; kt <= qt; ++kt) {
            const int cur = kt & 1;

            // prefetch kt+1 into the other set (overlaps with compute below)
            if (kt < qt) {
                const int nxt = cur ^ 1;
#pragma unroll
                for (int i = 0; i < 4; ++i) {
                    async16(&Kh[(size_t)((kt + 1) * 64 + i * 16 + ln) * HN_ + w * 32 + quad * 8],
                            &Ks[nxt][((i * 4 + w) * 64 + l) * 8]);
                    int dv = i * 4 + w, dt = dv >> 1, ks = dv & 1;
                    async16(&Vh[(size_t)(dt * 16 + ln) * S_LEN + (kt + 1) * 64 + ks * 32 + quad * 8],
                            &Vs[nxt][(dv * 64 + l) * 8]);
                }
            }

            // S = Q K^T : 16 q rows x 64 k tokens per wave
            f32x4 sc[4];
#pragma unroll
            for (int nt = 0; nt < 4; ++nt)
#pragma unroll
                for (int r = 0; r < 4; ++r) sc[nt][r] = 0.f;
#pragma unroll
            for (int nt = 0; nt < 4; ++nt)
#pragma unroll
                for (int ks = 0; ks < 4; ++ks) {
                    bf16x8 kf = *(const bf16x8*)&Ks[cur][((nt * 4 + ks) * 64 + l) * 8];
                    sc[nt] = __builtin_amdgcn_mfma_f32_16x16x32_bf16(qf[ks], kf, sc[nt], 0, 0, 0);
                }

            if (kt == qt) {   // only the diagonal tile is partially masked
#pragma unroll
                for (int nt = 0; nt < 4; ++nt)
#pragma unroll
                    for (int r = 0; r < 4; ++r)
                        if (nt * 16 + ln > w * 16 + quad * 4 + r) sc[nt][r] = -1e30f;
            }

            // online softmax (base-2; scale folded into Q)
            float corr[4];
#pragma unroll
            for (int r = 0; r < 4; ++r) {
                float mx = fmaxf(fmaxf(sc[0][r], sc[1][r]), fmaxf(sc[2][r], sc[3][r]));
                mx = fmaxf(mx, __shfl_xor(mx, 1));
                mx = fmaxf(mx, __shfl_xor(mx, 2));
                mx = fmaxf(mx, __shfl_xor(mx, 4));
                mx = fmaxf(mx, __shfl_xor(mx, 8));
                float mnew = fmaxf(m_i[r], mx);
                corr[r] = exp2f(m_i[r] - mnew);
                m_i[r] = mnew;
            }
#pragma unroll
            for (int r = 0; r < 4; ++r) {
                float ps = 0.f;
#pragma unroll
                for (int nt = 0; nt < 4; ++nt) {
                    float p = exp2f(sc[nt][r] - m_i[r]);
                    ps += p;
                    Psm[w][quad * 4 + r][nt * 16 + ln] = f2bf(p);
                }
                l_i[r] = l_i[r] * corr[r] + ps;   // lane-partial l
            }

            // rescale O, then O += P @ V
#pragma unroll
            for (int dt = 0; dt < 8; ++dt)
#pragma unroll
                for (int r = 0; r < 4; ++r) acco[dt][r] *= corr[r];

            bf16x8 pf[2];
#pragma unroll
            for (int ks = 0; ks < 2; ++ks)
                pf[ks] = *(const bf16x8*)&Psm[w][ln][ks * 32 + quad * 8];
#pragma unroll
            for (int dt = 0; dt < 8; ++dt)
#pragma unroll
                for (int ks = 0; ks < 2; ++ks) {
                    bf16x8 vf = *(const bf16x8*)&Vs[cur][((dt * 2 + ks) * 64 + l) * 8];
                    acco[dt] = __builtin_amdgcn_mfma_f32_16x16x32_bf16(pf[ks], vf, acco[dt], 0, 0, 0);
                }
            __syncthreads();   // release cur set; drain the kt+1 prefetch
        }

        // finalize: reduce lane-partial l over the 16-lane quad group
#pragma unroll
        for (int r = 0; r < 4; ++r) {
            float s = l_i[r];
            s += __shfl_xor(s, 1);
            s += __shfl_xor(s, 2);
            s += __shfl_xor(s, 4);
            s += __shfl_xor(s, 8);
            l_i[r] = 1.f / s;
        }
#pragma unroll
        for (int dt = 0; dt < 8; ++dt)
#pragma unroll
            for (int r = 0; r < 4; ++r) {
                int srow = q0 + w * 16 + quad * 4 + r;
                Ctx[((size_t)(srow * B_SZ + b)) * H_DIM + n * HN_ + dt * 16 + ln] =
                    f2bf(acco[dt][r] * l_i[r]);
            }
    }
}

__global__ void copy_bias(const float* __restrict__ b_dense, float* __restrict__ out)
{
    int t = blockIdx.x * 256 + threadIdx.x;
    if (t < H_DIM) out[(size_t)M_TOK * H_DIM + t] = b_dense[t];
}

extern "C" void kernel_launch(void* const* d_in, const int* in_sizes, int n_in,
                              void* d_out, int out_size, void* d_ws, size_t ws_size,
                              hipStream_t stream)
{
    const float* hs      = (const float*)d_in[0];
    /* d_in[1] attention_mask: compile-time causal, ignored */
    const float* w_qkv   = (const float*)d_in[2];
    const float* b_qkv   = (const float*)d_in[3];
    const float* w_dense = (const float*)d_in[4];
    const float* b_dense = (const float*)d_in[5];
    float* out = (float*)d_out;

    u16* hs_bf = (u16*)d_ws;                           //  16.8 MB
    u16* wq_bf = hs_bf + (size_t)M_TOK * H_DIM;        //  25.2 MB
    u16* wd_bf = wq_bf + (size_t)NQKV * H_DIM;         //   8.4 MB
    u16* Qb    = wd_bf + (size_t)H_DIM * H_DIM;        //  16.8 MB  [b][n][s][d]
    u16* Kb    = Qb    + (size_t)M_TOK * H_DIM;        //  16.8 MB  [b][n][s][d]
    u16* Vt    = Kb    + (size_t)M_TOK * H_DIM;        //  16.8 MB  [b][n][d][s]
    u16* Ctx   = Vt    + (size_t)M_TOK * H_DIM;        //  16.8 MB  [s][b][h]

    const int g1 = (M_TOK * H_DIM) / 4;   // float4-groups per tensor
    const int g2 = (NQKV * H_DIM) / 4;
    const int g3 = (H_DIM * H_DIM) / 4;
    cvt3<<<(g1 + g2 + g3 + 255) / 256, 256, 0, stream>>>(
        hs, hs_bf, g1, w_qkv, wq_bf, g2, w_dense, wd_bf, g3);

    gemm8<1, M_TOK, NQKV><<<(M_TOK / 256) * (NQKV / 256), 512, 0, stream>>>(
        hs_bf, wq_bf, b_qkv, nullptr, Qb, Kb, Vt);

    attn_mfma<<<dim3(NT_ / 2, NH_, B_SZ), 256, 0, stream>>>(Qb, Kb, Vt, Ctx);

    gemm8<0, M_TOK, H_DIM><<<(M_TOK / 256) * (H_DIM / 256), 512, 0, stream>>>(
        Ctx, wd_bf, nullptr, out, nullptr, nullptr, nullptr);

    copy_bias<<<(H_DIM + 255) / 256, 256, 0, stream>>>(b_dense, out);
}